// Round 3
// baseline (107.730 us; speedup 1.0000x reference)
//
#include <hip/hip_runtime.h>

#define S 2000
#define P 2500
#define R 5
#define PT 4              // p-values per block
#define NPT (P / PT)      // 625
#define HALF (S / 2)      // 1000 float4 elements per row
#define NJ 4              // ceil(HALF/256)

typedef float floatx4 __attribute__((ext_vector_type(4)));

__global__ __launch_bounds__(256) void grad_kernel(
    const float* __restrict__ filtration,   // (S,2) interleaved
    const float* __restrict__ bars0,        // (P,R)
    const float* __restrict__ bars1,        // (P,R)
    const float* __restrict__ sample_pts,   // (P,2)
    float* __restrict__ gm0, float* __restrict__ gc0,
    float* __restrict__ gm1, float* __restrict__ gc1)
{
    int bid = blockIdx.x;                 // 2 * R * NPT = 6250
    int h = bid / (R * NPT);
    int rem = bid - h * (R * NPT);
    int r = rem / NPT;
    int pt = rem - r * NPT;
    int p0 = pt * PT;
    int tid = threadIdx.x;

    const float* bars = h ? bars1 : bars0;
    float* gm = h ? gm1 : gm0;
    float* gc = h ? gc1 : gc0;

    const float4* filt4 = (const float4*)filtration;

    // ---- cache filtration + per-element invariants in registers ----
    float4 f[NJ];
    float tx0[NJ], ty0[NJ], tx1[NJ], ty1[NJ], s0[NJ], s1[NJ];
#pragma unroll
    for (int it = 0; it < NJ; ++it) {
        int j = tid + 256 * it;
        float4 v = make_float4(0.f, 0.f, 0.f, 0.f);
        if (j < HALF) v = filt4[j];
        f[it] = v;
        // tol = ATOL + RTOL*|f|, per-op rounding (match numpy, no fma)
        tx0[it] = __fadd_rn(0.01f, __fmul_rn(1e-5f, __builtin_fabsf(v.x)));
        ty0[it] = __fadd_rn(0.01f, __fmul_rn(1e-5f, __builtin_fabsf(v.y)));
        tx1[it] = __fadd_rn(0.01f, __fmul_rn(1e-5f, __builtin_fabsf(v.z)));
        ty1[it] = __fadd_rn(0.01f, __fmul_rn(1e-5f, __builtin_fabsf(v.w)));
        s0[it] = v.x + v.y;
        s1[it] = v.z + v.w;
    }

    unsigned flags = 0;                    // 4 bits per pi
    size_t rowbase = ((size_t)r * P + p0) * (size_t)(2 * S);

#pragma unroll
    for (int pi = 0; pi < PT; ++pi) {
        int p = p0 + pi;
        float bar = bars[p * R + r];
        float scale = bar + 0.01f;         // GRID_RES
        float ptx = sample_pts[2 * p];
        float pty = sample_pts[2 * p + 1];
        float psum = ptx + pty;
        float lxk[5], lyk[5];
#pragma unroll
        for (int k = 0; k < 5; ++k) {
            float ks = (float)(k - 2) * scale;   // exact mul, k-2 in {-2..2}
            lxk[k] = ks + ptx;
            lyk[k] = ks + pty;
        }
        float lastx = lxk[4];
        float lasty = lyk[4];

        float axmax = 0.f, axmin = 0.f, aymax = 0.f, aymin = 0.f;
        float* gmrow = gm + rowbase + (size_t)pi * (size_t)(2 * S);

#pragma unroll
        for (int it = 0; it < NJ; ++it) {
            int j = tid + 256 * it;
            if (j < HALF) {
                floatx4 o;
                {   // pair 0
                    float fx = f[it].x, fy = f[it].y;
                    bool cx = false, cy = false;
#pragma unroll
                    for (int k = 0; k < 5; ++k) {
                        cx = cx || (__builtin_fabsf(lxk[k] - fx) <= tx0[it]);
                        cy = cy || (__builtin_fabsf(lyk[k] - fy) <= ty0[it]);
                    }
                    float fsum = s0[it];
                    bool above = fsum > psum;
                    bool below = fsum < psum;
                    float sgn = above ? 1.0f : (below ? -1.0f : 0.0f);
                    bool condx = cx && (fy <= lasty);
                    bool condy = cy && (fx <= lastx);
                    o.x = condx ? sgn : 0.0f;
                    o.y = condy ? sgn : 0.0f;
                }
                {   // pair 1
                    float fx = f[it].z, fy = f[it].w;
                    bool cx = false, cy = false;
#pragma unroll
                    for (int k = 0; k < 5; ++k) {
                        cx = cx || (__builtin_fabsf(lxk[k] - fx) <= tx1[it]);
                        cy = cy || (__builtin_fabsf(lyk[k] - fy) <= ty1[it]);
                    }
                    float fsum = s1[it];
                    bool above = fsum > psum;
                    bool below = fsum < psum;
                    float sgn = above ? 1.0f : (below ? -1.0f : 0.0f);
                    bool condx = cx && (fy <= lasty);
                    bool condy = cy && (fx <= lastx);
                    o.z = condx ? sgn : 0.0f;
                    o.w = condy ? sgn : 0.0f;
                }
                // gc accumulation via min/max (4 VALU instead of bit packing)
                axmax = fmaxf(axmax, fmaxf(o.x, o.z));
                axmin = fminf(axmin, fminf(o.x, o.z));
                aymax = fmaxf(aymax, fmaxf(o.y, o.w));
                aymin = fminf(aymin, fminf(o.y, o.w));
                __builtin_nontemporal_store(o, (floatx4*)(gmrow + (size_t)j * 4));
            }
        }
        unsigned b = 0;
        if (axmax > 0.f) b |= 1u;   // any upper_x
        if (axmin < 0.f) b |= 2u;   // any lower_x
        if (aymax > 0.f) b |= 4u;   // any upper_y
        if (aymin < 0.f) b |= 8u;   // any lower_y
        flags |= b << (4 * pi);
    }

    // ---- or-reduce flags across wave, then across block ----
#pragma unroll
    for (int m = 1; m < 64; m <<= 1)
        flags |= (unsigned)__shfl_xor((int)flags, m);

    __shared__ unsigned bflags;
    if (tid == 0) bflags = 0u;
    __syncthreads();
    if ((tid & 63) == 0 && flags) atomicOr(&bflags, flags);
    __syncthreads();

    if (tid < PT * 2) {
        int pi = tid >> 1;
        int c = tid & 1;
        unsigned b = (bflags >> (4 * pi)) & 0xFu;
        float v;
        if (c == 0) v = (b & 1u) ? -1.0f : ((b & 2u) ? 1.0f : 0.0f);
        else        v = (b & 4u) ? -1.0f : ((b & 8u) ? 1.0f : 0.0f);
        gc[((size_t)r * P + p0) * 2 + tid] = v;
    }
}

__global__ __launch_bounds__(256) void copy_out_kernel(
    const float* __restrict__ b0, const float* __restrict__ b1,
    float* __restrict__ out)
{
    int i = blockIdx.x * blockDim.x + threadIdx.x;
    if (i < P * R) {
        out[i] = b0[i];
        out[P * R + i] = b1[i];
    }
}

extern "C" void kernel_launch(void* const* d_in, const int* in_sizes, int n_in,
                              void* d_out, int out_size, void* d_ws, size_t ws_size,
                              hipStream_t stream) {
    const float* filtration = (const float*)d_in[0];   // (2000,2)
    const float* bars_h0    = (const float*)d_in[1];   // (2500,5)
    const float* bars_h1    = (const float*)d_in[2];   // (2500,5)
    const float* sample_pts = (const float*)d_in[3];   // (2500,2)

    float* out = (float*)d_out;
    float* o_stack = out;                                 // 2*P*R
    float* gm0     = o_stack + (size_t)2 * P * R;         // R*P*2S
    float* gc0     = gm0 + (size_t)R * P * 2 * S;         // R*P*2
    float* gm1     = gc0 + (size_t)R * P * 2;             // R*P*2S
    float* gc1     = gm1 + (size_t)R * P * 2 * S;         // R*P*2

    copy_out_kernel<<<(P * R + 255) / 256, 256, 0, stream>>>(bars_h0, bars_h1, o_stack);
    grad_kernel<<<2 * R * NPT, 256, 0, stream>>>(filtration, bars_h0, bars_h1, sample_pts,
                                                 gm0, gc0, gm1, gc1);
}

// Round 4
// 88.479 us; speedup vs baseline: 1.2176x; 1.2176x over previous
//
#include <hip/hip_runtime.h>

#define S 2000
#define P 2500
#define R 5
#define HALF (S / 2)      // 1000 float4 elements per row
#define NIT 16            // ceil(HALF/64) wave iterations

typedef float floatx4 __attribute__((ext_vector_type(4)));

// One wave (64 threads) per (h, r, p). No LDS, no barriers: gc via wave __any,
// out-copy fused (lane 0 writes its bar). Stores never drained inside the
// kernel -> block exit is cheap, stores overlap across blocks.
__global__ __launch_bounds__(64) void grad_kernel(
    const float* __restrict__ filtration,   // (S,2) interleaved
    const float* __restrict__ bars0,        // (P,R)
    const float* __restrict__ bars1,        // (P,R)
    const float* __restrict__ sample_pts,   // (P,2)
    float* __restrict__ out,                // (2,P,R)
    float* __restrict__ gm0, float* __restrict__ gc0,
    float* __restrict__ gm1, float* __restrict__ gc1)
{
    int bid = blockIdx.x;                 // h*(R*P) + r*P + p, p fastest
    int h = bid / (R * P);
    int rem = bid - h * (R * P);
    int r = rem / P;
    int p = rem - r * P;
    int lane = threadIdx.x;

    const float* bars = h ? bars1 : bars0;
    float* gm = h ? gm1 : gm0;
    float* gc = h ? gc1 : gc0;

    float bar = bars[p * R + r];
    float scale = bar + 0.01f;               // GRID_RES
    float ptx = sample_pts[2 * p];
    float pty = sample_pts[2 * p + 1];
    float psum = ptx + pty;

    float lxk[5], lyk[5];
#pragma unroll
    for (int k = 0; k < 5; ++k) {
        float ks = (float)(k - 2) * scale;   // exact mul, k-2 in {-2..2}
        lxk[k] = ks + ptx;                   // single rounding per element
        lyk[k] = ks + pty;
    }
    float lastx = lxk[4];
    float lasty = lyk[4];

    // fused out-copy (out[h,p,r] = bar)
    if (lane == 0) out[(size_t)h * P * R + p * R + r] = bar;

    const floatx4* filt4 = (const floatx4*)filtration;
    float* gmrow = gm + ((size_t)r * P + p) * (size_t)(2 * S);

    float axmax = 0.f, axmin = 0.f, aymax = 0.f, aymin = 0.f;

#pragma unroll
    for (int it = 0; it < NIT; ++it) {
        int j = lane + 64 * it;
        if (it < NIT - 1 || j < HALF) {      // compile-time for it<15
            floatx4 f = filt4[j];
            floatx4 o;
            {   // pair 0 (s = 2j)
                float fx = f.x, fy = f.y;
                float tolx = __fadd_rn(0.01f, __fmul_rn(1e-5f, __builtin_fabsf(fx)));
                float toly = __fadd_rn(0.01f, __fmul_rn(1e-5f, __builtin_fabsf(fy)));
                bool cx = false, cy = false;
#pragma unroll
                for (int k = 0; k < 5; ++k) {
                    cx = cx || (__builtin_fabsf(lxk[k] - fx) <= tolx);
                    cy = cy || (__builtin_fabsf(lyk[k] - fy) <= toly);
                }
                float fsum = fx + fy;
                bool above = fsum > psum;
                bool below = fsum < psum;
                float sgn = above ? 1.0f : (below ? -1.0f : 0.0f);
                o.x = (cx && (fy <= lasty)) ? sgn : 0.0f;
                o.y = (cy && (fx <= lastx)) ? sgn : 0.0f;
            }
            {   // pair 1 (s = 2j+1)
                float fx = f.z, fy = f.w;
                float tolx = __fadd_rn(0.01f, __fmul_rn(1e-5f, __builtin_fabsf(fx)));
                float toly = __fadd_rn(0.01f, __fmul_rn(1e-5f, __builtin_fabsf(fy)));
                bool cx = false, cy = false;
#pragma unroll
                for (int k = 0; k < 5; ++k) {
                    cx = cx || (__builtin_fabsf(lxk[k] - fx) <= tolx);
                    cy = cy || (__builtin_fabsf(lyk[k] - fy) <= toly);
                }
                float fsum = fx + fy;
                bool above = fsum > psum;
                bool below = fsum < psum;
                float sgn = above ? 1.0f : (below ? -1.0f : 0.0f);
                o.z = (cx && (fy <= lasty)) ? sgn : 0.0f;
                o.w = (cy && (fx <= lastx)) ? sgn : 0.0f;
            }
            axmax = fmaxf(axmax, fmaxf(o.x, o.z));
            axmin = fminf(axmin, fminf(o.x, o.z));
            aymax = fmaxf(aymax, fmaxf(o.y, o.w));
            aymin = fminf(aymin, fminf(o.y, o.w));
            *(floatx4*)(gmrow + (size_t)j * 4) = o;
        }
    }

    // wave-level any() for gc (no LDS, no barrier)
    bool anyUx = __any(axmax > 0.f);
    bool anyLx = __any(axmin < 0.f);
    bool anyUy = __any(aymax > 0.f);
    bool anyLy = __any(aymin < 0.f);
    if (lane == 0) {
        float cxv = anyUx ? -1.0f : (anyLx ? 1.0f : 0.0f);
        float cyv = anyUy ? -1.0f : (anyLy ? 1.0f : 0.0f);
        float2 v = make_float2(cxv, cyv);
        *(float2*)(gc + ((size_t)r * P + p) * 2) = v;
    }
}

extern "C" void kernel_launch(void* const* d_in, const int* in_sizes, int n_in,
                              void* d_out, int out_size, void* d_ws, size_t ws_size,
                              hipStream_t stream) {
    const float* filtration = (const float*)d_in[0];   // (2000,2)
    const float* bars_h0    = (const float*)d_in[1];   // (2500,5)
    const float* bars_h1    = (const float*)d_in[2];   // (2500,5)
    const float* sample_pts = (const float*)d_in[3];   // (2500,2)

    float* out = (float*)d_out;
    float* o_stack = out;                                 // 2*P*R
    float* gm0     = o_stack + (size_t)2 * P * R;         // R*P*2S
    float* gc0     = gm0 + (size_t)R * P * 2 * S;         // R*P*2
    float* gm1     = gc0 + (size_t)R * P * 2;             // R*P*2S
    float* gc1     = gm1 + (size_t)R * P * 2 * S;         // R*P*2

    grad_kernel<<<2 * R * P, 64, 0, stream>>>(filtration, bars_h0, bars_h1, sample_pts,
                                              o_stack, gm0, gc0, gm1, gc1);
}

// Round 5
// 86.653 us; speedup vs baseline: 1.2432x; 1.0211x over previous
//
#include <hip/hip_runtime.h>

#define S 2000
#define P 2500
#define R 5
#define HALF (S / 2)      // 1000 float4 elements per row
#define NIT 16            // ceil(HALF/64) wave iterations

typedef float floatx4 __attribute__((ext_vector_type(4)));

// 256-thread workgroups, 4 independent (h,r,p) jobs per WG (one per wave).
// No LDS, no barriers: gc via wave __any, out-copy fused. Consecutive p per
// block -> each WG writes a contiguous 64KB span of gm.
__global__ __launch_bounds__(256) void grad_kernel(
    const float* __restrict__ filtration,   // (S,2) interleaved
    const float* __restrict__ bars0,        // (P,R)
    const float* __restrict__ bars1,        // (P,R)
    const float* __restrict__ sample_pts,   // (P,2)
    float* __restrict__ out,                // (2,P,R)
    float* __restrict__ gm0, float* __restrict__ gc0,
    float* __restrict__ gm1, float* __restrict__ gc1)
{
    int job = blockIdx.x * 4 + (threadIdx.x >> 6);   // h*(R*P) + r*P + p
    int lane = threadIdx.x & 63;
    int h = job / (R * P);
    int rem = job - h * (R * P);
    int r = rem / P;
    int p = rem - r * P;

    const float* bars = h ? bars1 : bars0;
    float* gm = h ? gm1 : gm0;
    float* gc = h ? gc1 : gc0;

    float bar = bars[p * R + r];
    float scale = bar + 0.01f;               // GRID_RES
    float ptx = sample_pts[2 * p];
    float pty = sample_pts[2 * p + 1];
    float psum = ptx + pty;

    float lxk[5], lyk[5];
#pragma unroll
    for (int k = 0; k < 5; ++k) {
        float ks = (float)(k - 2) * scale;   // exact mul, k-2 in {-2..2}
        lxk[k] = ks + ptx;                   // single rounding per element
        lyk[k] = ks + pty;
    }
    float lastx = lxk[4];
    float lasty = lyk[4];

    // fused out-copy (out[h,p,r] = bar)
    if (lane == 0) out[(size_t)h * P * R + p * R + r] = bar;

    const floatx4* filt4 = (const floatx4*)filtration;
    float* gmrow = gm + ((size_t)r * P + p) * (size_t)(2 * S);

    float axmax = 0.f, axmin = 0.f, aymax = 0.f, aymin = 0.f;

#pragma unroll
    for (int it = 0; it < NIT; ++it) {
        int j = lane + 64 * it;
        if (it < NIT - 1 || j < HALF) {      // compile-time for it<15
            floatx4 f = filt4[j];
            floatx4 o;
            {   // pair 0 (s = 2j)
                float fx = f.x, fy = f.y;
                float tolx = __fadd_rn(0.01f, __fmul_rn(1e-5f, __builtin_fabsf(fx)));
                float toly = __fadd_rn(0.01f, __fmul_rn(1e-5f, __builtin_fabsf(fy)));
                bool cx = false, cy = false;
#pragma unroll
                for (int k = 0; k < 5; ++k) {
                    cx = cx || (__builtin_fabsf(lxk[k] - fx) <= tolx);
                    cy = cy || (__builtin_fabsf(lyk[k] - fy) <= toly);
                }
                float fsum = fx + fy;
                bool above = fsum > psum;
                bool below = fsum < psum;
                float sgn = above ? 1.0f : (below ? -1.0f : 0.0f);
                o.x = (cx && (fy <= lasty)) ? sgn : 0.0f;
                o.y = (cy && (fx <= lastx)) ? sgn : 0.0f;
            }
            {   // pair 1 (s = 2j+1)
                float fx = f.z, fy = f.w;
                float tolx = __fadd_rn(0.01f, __fmul_rn(1e-5f, __builtin_fabsf(fx)));
                float toly = __fadd_rn(0.01f, __fmul_rn(1e-5f, __builtin_fabsf(fy)));
                bool cx = false, cy = false;
#pragma unroll
                for (int k = 0; k < 5; ++k) {
                    cx = cx || (__builtin_fabsf(lxk[k] - fx) <= tolx);
                    cy = cy || (__builtin_fabsf(lyk[k] - fy) <= toly);
                }
                float fsum = fx + fy;
                bool above = fsum > psum;
                bool below = fsum < psum;
                float sgn = above ? 1.0f : (below ? -1.0f : 0.0f);
                o.z = (cx && (fy <= lasty)) ? sgn : 0.0f;
                o.w = (cy && (fx <= lastx)) ? sgn : 0.0f;
            }
            axmax = fmaxf(axmax, fmaxf(o.x, o.z));
            axmin = fminf(axmin, fminf(o.x, o.z));
            aymax = fmaxf(aymax, fmaxf(o.y, o.w));
            aymin = fminf(aymin, fminf(o.y, o.w));
            *(floatx4*)(gmrow + (size_t)j * 4) = o;
        }
    }

    // wave-level any() for gc (no LDS, no barrier)
    bool anyUx = __any(axmax > 0.f);
    bool anyLx = __any(axmin < 0.f);
    bool anyUy = __any(aymax > 0.f);
    bool anyLy = __any(aymin < 0.f);
    if (lane == 0) {
        float cxv = anyUx ? -1.0f : (anyLx ? 1.0f : 0.0f);
        float cyv = anyUy ? -1.0f : (anyLy ? 1.0f : 0.0f);
        float2 v = make_float2(cxv, cyv);
        *(float2*)(gc + ((size_t)r * P + p) * 2) = v;
    }
}

extern "C" void kernel_launch(void* const* d_in, const int* in_sizes, int n_in,
                              void* d_out, int out_size, void* d_ws, size_t ws_size,
                              hipStream_t stream) {
    const float* filtration = (const float*)d_in[0];   // (2000,2)
    const float* bars_h0    = (const float*)d_in[1];   // (2500,5)
    const float* bars_h1    = (const float*)d_in[2];   // (2500,5)
    const float* sample_pts = (const float*)d_in[3];   // (2500,2)

    float* out = (float*)d_out;
    float* o_stack = out;                                 // 2*P*R
    float* gm0     = o_stack + (size_t)2 * P * R;         // R*P*2S
    float* gc0     = gm0 + (size_t)R * P * 2 * S;         // R*P*2
    float* gm1     = gc0 + (size_t)R * P * 2;             // R*P*2S
    float* gc1     = gm1 + (size_t)R * P * 2 * S;         // R*P*2

    grad_kernel<<<(2 * R * P) / 4, 256, 0, stream>>>(filtration, bars_h0, bars_h1, sample_pts,
                                                     o_stack, gm0, gc0, gm1, gc1);
}